// Round 8
// baseline (438.795 us; speedup 1.0000x reference)
//
#include <hip/hip_runtime.h>
#include <cmath>

// FullyConnectedTensorProductRescaleSwishGate — MI355X bf16-MFMA, round 8.
//
// Evidence across R3..R7: this dispatch co-schedules ~1 workgroup per CU
// (occupancy ≈ blocksize/64 waves in EVERY config; residency arithmetic on
// R3 gives 0.95 blocks/CU). So waves/CU is set by BLOCK SIZE alone.
// R8: 1024-thread blocks (16 waves = 4/SIMD), BM=64, non-persistent,
// R3's proven load path (global->reg->convert->LDS; L3-friendly, no DMA,
// no NT hints — R7 showed NT loads bypass L3 and NT stores cause RMW).
// Weight L2 traffic halves (each weight byte feeds 64 rows).
//
// Math (per row): features A (K=768) = [x0 | dot=x1*y1 | x1_0 | x1_1 | x1_2]
//   u0=x0@C0W0, d1=dot@C1W1, u2=x0@C2W2, d3=dot@C3W3, u4=x0@C4W4,
//   r_i=x1_i@C5W5, q_i=x1_i@C6W6
//   s1=y0*u0+d1 ; s2=y0*u2+d3 ; v_i=y1_i*u4+y0*r_i+y1_{j2}*q_{j1}-y1_{j1}*q_{j2}
//
// Wave layout (16 waves): w = rg*4+cw; rg=row-group (16 rows), cw=col-wave.
//   pass 1: S1 col-tiles {cw,cw+4,cw+8,cw+12}  (48 MFMA/wave)
//   pass 2: S2/V col-tiles {cw, cw+4}, sequential (88 MFMA/wave)
// Two passes keep live accs <= 9 f32x4 so 1024-thr fits 128 VGPR/wave.

typedef __bf16 bf16_t;
typedef bf16_t bf16x8 __attribute__((ext_vector_type(8)));
typedef bf16_t bf16x4 __attribute__((ext_vector_type(4)));
typedef float  f32x4  __attribute__((ext_vector_type(4)));

#define BM 64
#define KP 768          // feature row stride (elems) = 1536 B

// weight group offsets in d_ws (bf16 elems), stored [col][k], pre-scaled
#define WU0 0           // 256 x 256
#define WD1 65536       // 256 x 128
#define WU2 98304       // 128 x 256
#define WD3 131072      // 128 x 128
#define WU4 147456      // 128 x 256
#define WR  180224      // 128 x 128
#define WQ  196608      // 128 x 128
#define WTOT 212992

#define MFMA(acc, av, bv) acc = __builtin_amdgcn_mfma_f32_16x16x32_bf16(av, bv, acc, 0, 0, 0)

__global__ void prep_weights(const float* __restrict__ W0, const float* __restrict__ W1,
                             const float* __restrict__ W2, const float* __restrict__ W3,
                             const float* __restrict__ W4, const float* __restrict__ W5,
                             const float* __restrict__ W6, bf16_t* __restrict__ WT,
                             float c0, float c1, float c2, float c3,
                             float c4, float c5, float c6)
{
    int idx = blockIdx.x * 256 + threadIdx.x;
    if (idx >= WTOT) return;
    float v;
    if (idx < WD1)      { int c = idx >> 8, k = idx & 255;                    v = c0 * W0[k * 256 + c]; }
    else if (idx < WU2) { int j = idx - WD1; int c = j >> 7, k = j & 127;     v = c1 * W1[k * 256 + c]; }
    else if (idx < WD3) { int j = idx - WU2; int c = j >> 8, k = j & 255;     v = c2 * W2[k * 128 + c]; }
    else if (idx < WU4) { int j = idx - WD3; int c = j >> 7, k = j & 127;     v = c3 * W3[k * 128 + c]; }
    else if (idx < WR)  { int j = idx - WU4; int c = j >> 8, k = j & 255;     v = c4 * W4[k * 128 + c]; }
    else if (idx < WQ)  { int j = idx - WR;  int c = j >> 7, k = j & 127;     v = c5 * W5[k * 128 + c]; }
    else                { int j = idx - WQ;  int c = j >> 7, k = j & 127;     v = c6 * W6[k * 128 + c]; }
    WT[idx] = (bf16_t)v;
}

__global__ __launch_bounds__(1024) void tp_fused(
    const float* __restrict__ x, const float* __restrict__ y,
    const float* __restrict__ bias, const bf16_t* __restrict__ WT,
    float* __restrict__ out, int n, float inv, float silu_c, float sig_c)
{
    __shared__ __attribute__((aligned(16))) bf16_t A[BM * KP];   // 96 KB
    __shared__ float Ylds[BM][4];                                 // 1 KB

    const int tid = threadIdx.x;
    const int l   = tid & 63;
    const int w   = tid >> 6;          // wave 0..15
    const int rg  = w >> 2;            // row-group 0..3 (16 rows each)
    const int cw  = w & 3;             // col-wave 0..3
    const int l15 = l & 15;
    const int lg  = l >> 4;
    const int klane = lg * 8;
    const int z0  = blockIdx.x * BM;

    // ---- y -> LDS (epilogue use; row-clamped for tail block) ----
    if (tid < BM * 4) {
        int r = tid >> 2, c = tid & 3;
        int zr = z0 + r; if (zr >= n) zr = n - 1;
        Ylds[r][c] = y[(size_t)zr * 4 + c];
    }

    // ---- feature build: global -> regs -> bf16 A (XOR bank swizzle) ----
    #pragma unroll
    for (int it = 0; it < 4; ++it) {                 // x0 block (64x256 f32)
        int f4 = tid + it * 1024;
        int r = f4 >> 6, c4 = f4 & 63;
        int zr = z0 + r; if (zr >= n) zr = n - 1;
        float4 xv = *(const float4*)(x + (size_t)zr * 640 + c4 * 4);
        bf16x4 o;
        o[0] = (bf16_t)xv.x; o[1] = (bf16_t)xv.y;
        o[2] = (bf16_t)xv.z; o[3] = (bf16_t)xv.w;
        *(bf16x4*)&A[r * KP + ((c4 * 4) ^ ((r & 7) << 3))] = o;
    }
    #pragma unroll
    for (int s = 0; s < 2; ++s) {                    // dot + x1 de-interleave
        int r = (tid >> 5) + s * 32;
        int zr = z0 + r; if (zr >= n) zr = n - 1;
        const float* xp = x + (size_t)zr * 640 + 256 + (tid & 31) * 12;
        float4 A0 = *(const float4*)(xp);
        float4 A1 = *(const float4*)(xp + 4);
        float4 A2 = *(const float4*)(xp + 8);
        float4 yv = *(const float4*)(y + (size_t)zr * 4);   // broadcast in 32-group
        int sw = (r & 7) << 3, base = r * KP;
        int uq = (tid & 31) * 4;
        bf16x4 dq, e0, e1, e2;
        dq[0] = (bf16_t)(A0.x*yv.y + A0.y*yv.z + A0.z*yv.w);
        dq[1] = (bf16_t)(A0.w*yv.y + A1.x*yv.z + A1.y*yv.w);
        dq[2] = (bf16_t)(A1.z*yv.y + A1.w*yv.z + A2.x*yv.w);
        dq[3] = (bf16_t)(A2.y*yv.y + A2.z*yv.z + A2.w*yv.w);
        e0[0]=(bf16_t)A0.x; e0[1]=(bf16_t)A0.w; e0[2]=(bf16_t)A1.z; e0[3]=(bf16_t)A2.y;
        e1[0]=(bf16_t)A0.y; e1[1]=(bf16_t)A1.x; e1[2]=(bf16_t)A1.w; e1[3]=(bf16_t)A2.z;
        e2[0]=(bf16_t)A0.z; e2[1]=(bf16_t)A1.y; e2[2]=(bf16_t)A2.x; e2[3]=(bf16_t)A2.w;
        *(bf16x4*)&A[base + ((256 + uq) ^ sw)] = dq;
        *(bf16x4*)&A[base + ((384 + uq) ^ sw)] = e0;
        *(bf16x4*)&A[base + ((512 + uq) ^ sw)] = e1;
        *(bf16x4*)&A[base + ((640 + uq) ^ sw)] = e2;
    }
    __syncthreads();

    const int asw    = (l15 & 7) << 3;
    const int a0base = (rg * 16 + l15) * KP;

    // ================= pass 1: S1 (4 col-tiles per wave) =================
    {
        const bf16_t* bS[4]; const bf16_t* bD[4];
        #pragma unroll
        for (int t = 0; t < 4; ++t) {
            int ct = cw + 4 * t;
            bS[t] = WT + WU0 + (ct * 16 + l15) * 256 + klane;
            bD[t] = WT + WD1 + (ct * 16 + l15) * 128 + klane;
        }
        f32x4 sU[4], sD4[4];
        #pragma unroll
        for (int t = 0; t < 4; ++t) { f32x4 z = {0.f,0.f,0.f,0.f}; sU[t] = z; sD4[t] = z; }

        #pragma unroll
        for (int kk = 0; kk < 8; ++kk) {             // u0 over x0 block
            bf16x8 a0 = *(const bf16x8*)&A[a0base + ((kk * 32 + klane) ^ asw)];
            #pragma unroll
            for (int t = 0; t < 4; ++t) {
                bf16x8 bb = *(const bf16x8*)(bS[t] + kk * 32);
                MFMA(sU[t], a0, bb);
            }
        }
        #pragma unroll
        for (int kk = 0; kk < 4; ++kk) {             // d1 over dot block
            bf16x8 a0 = *(const bf16x8*)&A[a0base + ((256 + kk * 32 + klane) ^ asw)];
            #pragma unroll
            for (int t = 0; t < 4; ++t) {
                bf16x8 bb = *(const bf16x8*)(bD[t] + kk * 32);
                MFMA(sD4[t], a0, bb);
            }
        }
        #pragma unroll
        for (int t = 0; t < 4; ++t) {                // epilogue: silu, guarded store
            int col = (cw + 4 * t) * 16 + l15;
            float bv = bias[col];
            #pragma unroll
            for (int reg = 0; reg < 4; ++reg) {
                int lr = rg * 16 + lg * 4 + reg;
                int zr = z0 + lr;
                if (zr < n) {
                    float sv = (Ylds[lr][0] * sU[t][reg] + sD4[t][reg]) * inv + bv;
                    out[(size_t)zr * 640 + col] = silu_c * sv / (1.0f + __expf(-sv));
                }
            }
        }
    }

    // ============ pass 2: S2 + V (2 col-tiles per wave, sequential) ============
    #pragma unroll
    for (int t2 = 0; t2 < 2; ++t2) {
        int ct = cw + 4 * t2;
        const bf16_t* pu2 = WT + WU2 + (ct * 16 + l15) * 256 + klane;
        const bf16_t* pd3 = WT + WD3 + (ct * 16 + l15) * 128 + klane;
        const bf16_t* pu4 = WT + WU4 + (ct * 16 + l15) * 256 + klane;
        const bf16_t* pr  = WT + WR  + (ct * 16 + l15) * 128 + klane;
        const bf16_t* pq  = WT + WQ  + (ct * 16 + l15) * 128 + klane;

        f32x4 vU2, vD3, vU4, vR[3], vQ[3];
        { f32x4 z = {0.f,0.f,0.f,0.f}; vU2 = z; vD3 = z; vU4 = z;
          #pragma unroll
          for (int i = 0; i < 3; ++i) { vR[i] = z; vQ[i] = z; } }

        #pragma unroll
        for (int kk = 0; kk < 8; ++kk) {             // u2 & u4 over x0 block
            bf16x8 a0 = *(const bf16x8*)&A[a0base + ((kk * 32 + klane) ^ asw)];
            bf16x8 bb;
            bb = *(const bf16x8*)(pu2 + kk * 32); MFMA(vU2, a0, bb);
            bb = *(const bf16x8*)(pu4 + kk * 32); MFMA(vU4, a0, bb);
        }
        #pragma unroll
        for (int kk = 0; kk < 4; ++kk) {             // d3 over dot block
            bf16x8 a0 = *(const bf16x8*)&A[a0base + ((256 + kk * 32 + klane) ^ asw)];
            bf16x8 bb = *(const bf16x8*)(pd3 + kk * 32);
            MFMA(vD3, a0, bb);
        }
        #pragma unroll
        for (int kk = 0; kk < 4; ++kk) {             // r_i & q_i; B frags shared over i
            bf16x8 brr = *(const bf16x8*)(pr + kk * 32);
            bf16x8 bqq = *(const bf16x8*)(pq + kk * 32);
            #pragma unroll
            for (int i = 0; i < 3; ++i) {
                int kb = 384 + i * 128 + kk * 32;
                bf16x8 a0 = *(const bf16x8*)&A[a0base + ((kb + klane) ^ asw)];
                MFMA(vR[i], a0, brr);
                MFMA(vQ[i], a0, bqq);
            }
        }

        // epilogue: gate + cross recombination, guarded 12B stores
        int col = ct * 16 + l15;
        float b2v = bias[256 + col];
        #pragma unroll
        for (int reg = 0; reg < 4; ++reg) {
            int lr = rg * 16 + lg * 4 + reg;
            int zr = z0 + lr;
            if (zr < n) {
                f32x4 yv = *(const f32x4*)&Ylds[lr][0];
                float sv = (yv[0] * vU2[reg] + vD3[reg]) * inv + b2v;
                float g  = sig_c * inv / (1.0f + __expf(-sv));
                float u4v = vU4[reg];
                float v0 = yv[1] * u4v + yv[0] * vR[0][reg] + yv[3] * vQ[1][reg] - yv[2] * vQ[2][reg];
                float v1 = yv[2] * u4v + yv[0] * vR[1][reg] + yv[1] * vQ[2][reg] - yv[3] * vQ[0][reg];
                float v2 = yv[3] * u4v + yv[0] * vR[2][reg] + yv[2] * vQ[0][reg] - yv[1] * vQ[1][reg];
                size_t base = (size_t)zr * 640 + 256 + (size_t)col * 3;
                out[base + 0] = v0 * g;
                out[base + 1] = v1 * g;
                out[base + 2] = v2 * g;
            }
        }
    }
}

extern "C" void kernel_launch(void* const* d_in, const int* in_sizes, int n_in,
                              void* d_out, int out_size, void* d_ws, size_t ws_size,
                              hipStream_t stream)
{
    (void)n_in; (void)out_size; (void)ws_size;
    const float* x  = (const float*)d_in[0];
    const float* y  = (const float*)d_in[1];
    const float* W0 = (const float*)d_in[2];
    const float* W1 = (const float*)d_in[3];
    const float* W2 = (const float*)d_in[4];
    const float* W3 = (const float*)d_in[5];
    const float* W4 = (const float*)d_in[6];
    const float* W5 = (const float*)d_in[7];
    const float* W6 = (const float*)d_in[8];
    const float* b  = (const float*)d_in[9];
    float* out = (float*)d_out;

    const int n = in_sizes[0] / 640;                // 100000

    bf16_t* WT = (bf16_t*)d_ws;                     // 212,992 bf16 = 425,984 B

    const double c0 = std::sqrt(256.0 * 256.0 / 384.0);
    const double c1 = std::sqrt(256.0 * 128.0 / 384.0) / std::sqrt(3.0);
    const double c2 = std::sqrt(128.0 * 256.0 / 384.0);
    const double c3 = std::sqrt(128.0 * 128.0 / 384.0) / std::sqrt(3.0);
    const double c4 = std::sqrt(3.0 * 128.0 * 256.0 / 512.0) / std::sqrt(3.0);
    const double c5 = std::sqrt(3.0 * 128.0 * 128.0 / 512.0) / std::sqrt(3.0);
    const double c6 = std::sqrt(3.0 * 128.0 * 128.0 / 512.0) / std::sqrt(6.0);
    const double inv = 1.0 / std::sqrt(2560.0);

    // second moments of silu/sigmoid under N(0,1) via Simpson (matches hermgauss)
    double m_silu = 0.0, m_sig = 0.0;
    {
        const int M = 24000;
        const double a = -12.0, h = 24.0 / M;
        for (int k = 0; k <= M; ++k) {
            double t = a + h * k;
            double wgt = (k == 0 || k == M) ? 1.0 : ((k & 1) ? 4.0 : 2.0);
            double sg = 1.0 / (1.0 + std::exp(-t));
            double phi = std::exp(-0.5 * t * t) * 0.3989422804014327;
            m_silu += wgt * (t * sg) * (t * sg) * phi;
            m_sig  += wgt * sg * sg * phi;
        }
        m_silu *= h / 3.0; m_sig *= h / 3.0;
    }
    const float silu_c = (float)(1.0 / std::sqrt(m_silu));
    const float sig_c  = (float)(1.0 / std::sqrt(m_sig));

    prep_weights<<<(WTOT + 255) / 256, 256, 0, stream>>>(
        W0, W1, W2, W3, W4, W5, W6, WT,
        (float)c0, (float)c1, (float)c2, (float)c3, (float)c4, (float)c5, (float)c6);

    const int grid = (n + BM - 1) / BM;             // 1563
    tp_fused<<<grid, 1024, 0, stream>>>(x, y, b, WT, out, n,
                                        (float)inv, silu_c, sig_c);
}

// Round 9
// 267.284 us; speedup vs baseline: 1.6417x; 1.6417x over previous
//
#include <hip/hip_runtime.h>
#include <cmath>

// FullyConnectedTensorProductRescaleSwishGate — MI355X bf16-MFMA, round 9.
//
// Model update (explains R3-R8): the gfx950 register file is UNIFIED
// (VGPR+AGPR); rocprof's VGPR_Count excludes AGPR accumulators. Every prior
// round was 1 block/CU by register arithmetic (e.g. R4: 72+104agpr=176/wave
// -> 2 waves/SIMD -> exactly one 8-wave block). R8 additionally starved B
// (1 MFMA per B-frag, 4x redundant panel reads = 1.7 MB L2/block, exposed).
//
// R9: BM=64, 1024 thr = 16 waves (4/SIMD), wave = (rg in 0..1) x (cw in 0..7).
//  - each wave owns 2 row-tiles -> 2 MFMAs per B-frag; B/block = 852 KB
//  - explicit depth-2 B prefetch (named regs, fully unrolled) -> loads in
//    flight; 16-wave TLP covers the rest
//  - budget <=128 regs/wave total so the 16-wave block actually fits
//  - S pass: col-tiles {cw, cw+8 (S1), cw+16 (S2->gate stays in regs)}
//  - V pass: col-tile cw; r/q B-frags amortized 12 MFMA each
//
// Math (per row): A (K=768) = [x0 | dot=x1*y1 | x1_0 | x1_1 | x1_2]
//   s1=y0*(x0@C0W0)+dot@C1W1 ; s2=y0*(x0@C2W2)+dot@C3W3
//   v_i=y1_i*(x0@C4W4)+y0*(x1_i@C5W5)+y1_{i+2}*q_{i+1}-y1_{i+1}*q_{i+2},
//   q_a=x1_a@C6W6.  out=[SILU_C*silu(s1*inv+b0), v*inv*SIG_C*sigmoid(s2*inv+b1)]

typedef __bf16 bf16_t;
typedef bf16_t bf16x8 __attribute__((ext_vector_type(8)));
typedef bf16_t bf16x4 __attribute__((ext_vector_type(4)));
typedef float  f32x4  __attribute__((ext_vector_type(4)));

#define BM 64
#define KP 768          // feature row stride (elems) = 1536 B

#define MFMA(acc, av, bv) acc = __builtin_amdgcn_mfma_f32_16x16x32_bf16(av, bv, acc, 0, 0, 0)

// WsT: 384 cols x 384 k  (cols 0-255 = s1 via C0W0/C1W1; 256-383 = s2 via C2W2/C3W3)
// WvT: 128 cols x 512 k  (k 0-255 = C4W4; 256-383 = C5W5; 384-511 = C6W6)
__global__ void prep_weights(const float* __restrict__ W0, const float* __restrict__ W1,
                             const float* __restrict__ W2, const float* __restrict__ W3,
                             const float* __restrict__ W4, const float* __restrict__ W5,
                             const float* __restrict__ W6,
                             bf16_t* __restrict__ WsT, bf16_t* __restrict__ WvT,
                             float c0, float c1, float c2, float c3,
                             float c4, float c5, float c6)
{
    int idx = blockIdx.x * 256 + threadIdx.x;
    if (idx < 384 * 384) {
        int col = idx / 384, k = idx % 384;
        float v;
        if (col < 256)
            v = (k < 256) ? c0 * W0[k * 256 + col] : c1 * W1[(k - 256) * 256 + col];
        else {
            int c = col - 256;
            v = (k < 256) ? c2 * W2[k * 128 + c] : c3 * W3[(k - 256) * 128 + c];
        }
        WsT[idx] = (bf16_t)v;
    } else if (idx < 384 * 384 + 128 * 512) {
        int j = idx - 384 * 384;
        int col = j / 512, k = j % 512;
        float v = (k < 256) ? c4 * W4[k * 128 + col]
                : (k < 384) ? c5 * W5[(k - 256) * 128 + col]
                            : c6 * W6[(k - 384) * 128 + col];
        WvT[j] = (bf16_t)v;
    }
}

__global__ __launch_bounds__(1024) void tp_fused(
    const float* __restrict__ x, const float* __restrict__ y,
    const float* __restrict__ bias,
    const bf16_t* __restrict__ WsT, const bf16_t* __restrict__ WvT,
    float* __restrict__ out, int n, float inv, float silu_c, float sig_c)
{
    __shared__ __attribute__((aligned(16))) bf16_t A[BM * KP];   // 96 KB
    __shared__ float Ylds[BM][4];                                 // 1 KB

    const int tid = threadIdx.x;
    const int l   = tid & 63;
    const int w   = tid >> 6;          // wave 0..15
    const int rg  = w >> 3;            // row-group 0..1 (32 rows each)
    const int cw  = w & 7;             // col-wave 0..7
    const int l15 = l & 15;
    const int lg  = l >> 4;
    const int klane = lg * 8;
    const int z0  = blockIdx.x * BM;

    // loop-invariant bias values in registers
    const float bias_s0 = bias[(cw    ) * 16 + l15];
    const float bias_s1 = bias[(cw + 8) * 16 + l15];
    const float bias_g  = bias[256 + cw * 16 + l15];

    // ---- y -> LDS (epilogue use; row-clamped for tail block) ----
    if (tid < BM * 4) {
        int r = tid >> 2, c = tid & 3;
        int zr = z0 + r; if (zr >= n) zr = n - 1;
        Ylds[r][c] = y[(size_t)zr * 4 + c];
    }

    // ---- feature build: global -> regs -> bf16 A (XOR bank swizzle) ----
    #pragma unroll
    for (int it = 0; it < 4; ++it) {                 // x0 block (64x256 f32)
        int f4 = tid + it * 1024;
        int r = f4 >> 6, c4 = f4 & 63;
        int zr = z0 + r; if (zr >= n) zr = n - 1;
        float4 xv = *(const float4*)(x + (size_t)zr * 640 + c4 * 4);
        bf16x4 o;
        o[0] = (bf16_t)xv.x; o[1] = (bf16_t)xv.y;
        o[2] = (bf16_t)xv.z; o[3] = (bf16_t)xv.w;
        *(bf16x4*)&A[r * KP + ((c4 * 4) ^ ((r & 7) << 3))] = o;
    }
    #pragma unroll
    for (int s = 0; s < 2; ++s) {                    // dot + x1 de-interleave
        int r = (tid >> 5) + s * 32;
        int zr = z0 + r; if (zr >= n) zr = n - 1;
        const float* xp = x + (size_t)zr * 640 + 256 + (tid & 31) * 12;
        float4 A0 = *(const float4*)(xp);
        float4 A1 = *(const float4*)(xp + 4);
        float4 A2 = *(const float4*)(xp + 8);
        float4 yv = *(const float4*)(y + (size_t)zr * 4);
        int sw = (r & 7) << 3, base = r * KP;
        int uq = (tid & 31) * 4;
        bf16x4 dq, e0, e1, e2;
        dq[0] = (bf16_t)(A0.x*yv.y + A0.y*yv.z + A0.z*yv.w);
        dq[1] = (bf16_t)(A0.w*yv.y + A1.x*yv.z + A1.y*yv.w);
        dq[2] = (bf16_t)(A1.z*yv.y + A1.w*yv.z + A2.x*yv.w);
        dq[3] = (bf16_t)(A2.y*yv.y + A2.z*yv.z + A2.w*yv.w);
        e0[0]=(bf16_t)A0.x; e0[1]=(bf16_t)A0.w; e0[2]=(bf16_t)A1.z; e0[3]=(bf16_t)A2.y;
        e1[0]=(bf16_t)A0.y; e1[1]=(bf16_t)A1.x; e1[2]=(bf16_t)A1.w; e1[3]=(bf16_t)A2.z;
        e2[0]=(bf16_t)A0.z; e2[1]=(bf16_t)A1.y; e2[2]=(bf16_t)A2.x; e2[3]=(bf16_t)A2.w;
        *(bf16x4*)&A[base + ((256 + uq) ^ sw)] = dq;
        *(bf16x4*)&A[base + ((384 + uq) ^ sw)] = e0;
        *(bf16x4*)&A[base + ((512 + uq) ^ sw)] = e1;
        *(bf16x4*)&A[base + ((640 + uq) ^ sw)] = e2;
    }
    __syncthreads();

    const int asw    = (l15 & 7) << 3;
    const int a0base = (rg * 32 + l15) * KP;
    const int a1base = (rg * 32 + 16 + l15) * KP;

    f32x4 g2[2];                                     // gates (sig of s2), reg-resident

    // ================= S pass: tiles {cw, cw+8, cw+16}, K=384 =================
    {
        const bf16_t* p0 = WsT + ((cw     ) * 16 + l15) * 384 + klane;
        const bf16_t* p1 = WsT + ((cw + 8 ) * 16 + l15) * 384 + klane;
        const bf16_t* p2 = WsT + ((cw + 16) * 16 + l15) * 384 + klane;

        f32x4 aU[3][2], aD[3][2];
        #pragma unroll
        for (int t = 0; t < 3; ++t)
            #pragma unroll
            for (int r = 0; r < 2; ++r) { f32x4 z = {0.f,0.f,0.f,0.f}; aU[t][r] = z; aD[t][r] = z; }

        // depth-2 B prefetch (all indices static under full unroll)
        bf16x8 c0 = *(const bf16x8*)(p0);
        bf16x8 c1 = *(const bf16x8*)(p1);
        bf16x8 c2 = *(const bf16x8*)(p2);
        bf16x8 d0 = *(const bf16x8*)(p0 + 32);
        bf16x8 d1 = *(const bf16x8*)(p1 + 32);
        bf16x8 d2 = *(const bf16x8*)(p2 + 32);
        #pragma unroll
        for (int kk = 0; kk < 12; ++kk) {
            bf16x8 n0, n1, n2;
            if (kk < 10) {
                n0 = *(const bf16x8*)(p0 + (kk + 2) * 32);
                n1 = *(const bf16x8*)(p1 + (kk + 2) * 32);
                n2 = *(const bf16x8*)(p2 + (kk + 2) * 32);
            }
            bf16x8 a0 = *(const bf16x8*)&A[a0base + ((kk * 32 + klane) ^ asw)];
            bf16x8 a1 = *(const bf16x8*)&A[a1base + ((kk * 32 + klane) ^ asw)];
            if (kk < 8) {       // x0 block -> U accumulators
                MFMA(aU[0][0], a0, c0); MFMA(aU[0][1], a1, c0);
                MFMA(aU[1][0], a0, c1); MFMA(aU[1][1], a1, c1);
                MFMA(aU[2][0], a0, c2); MFMA(aU[2][1], a1, c2);
            } else {            // dot block -> D accumulators
                MFMA(aD[0][0], a0, c0); MFMA(aD[0][1], a1, c0);
                MFMA(aD[1][0], a0, c1); MFMA(aD[1][1], a1, c1);
                MFMA(aD[2][0], a0, c2); MFMA(aD[2][1], a1, c2);
            }
            if (kk < 10)      { c0 = d0; d0 = n0; c1 = d1; d1 = n1; c2 = d2; d2 = n2; }
            else if (kk == 10){ c0 = d0; c1 = d1; c2 = d2; }
        }

        // ---- S epilogue: S1 silu stores; S2 -> gates in regs ----
        #pragma unroll
        for (int t = 0; t < 2; ++t) {
            int col = (cw + 8 * t) * 16 + l15;
            float bv = t ? bias_s1 : bias_s0;
            #pragma unroll
            for (int rt = 0; rt < 2; ++rt)
                #pragma unroll
                for (int rq = 0; rq < 4; ++rq) {
                    int lr = rg * 32 + rt * 16 + lg * 4 + rq;
                    int zr = z0 + lr;
                    float sv = (Ylds[lr][0] * aU[t][rt][rq] + aD[t][rt][rq]) * inv + bv;
                    if (zr < n)
                        out[(size_t)zr * 640 + col] = silu_c * sv / (1.0f + __expf(-sv));
                }
        }
        #pragma unroll
        for (int rt = 0; rt < 2; ++rt)
            #pragma unroll
            for (int rq = 0; rq < 4; ++rq) {
                int lr = rg * 32 + rt * 16 + lg * 4 + rq;
                float sv = (Ylds[lr][0] * aU[2][rt][rq] + aD[2][rt][rq]) * inv + bias_g;
                g2[rt][rq] = sig_c * inv / (1.0f + __expf(-sv));
            }
    }

    // ================= V pass: tile cw, K families from WvT =================
    {
        const bf16_t* pV = WvT + (cw * 16 + l15) * 512 + klane;

        f32x4 vU4[2], vR[3][2], vQ[3][2];
        #pragma unroll
        for (int r = 0; r < 2; ++r) { f32x4 z = {0.f,0.f,0.f,0.f}; vU4[r] = z; }
        #pragma unroll
        for (int i = 0; i < 3; ++i)
            #pragma unroll
            for (int r = 0; r < 2; ++r) { f32x4 z = {0.f,0.f,0.f,0.f}; vR[i][r] = z; vQ[i][r] = z; }

        // u4: k 0..255 (A x0 region), depth-2 prefetch on the single stream
        bf16x8 vc = *(const bf16x8*)(pV);
        bf16x8 vd = *(const bf16x8*)(pV + 32);
        #pragma unroll
        for (int kk = 0; kk < 8; ++kk) {
            bf16x8 vn;
            if (kk < 6) vn = *(const bf16x8*)(pV + (kk + 2) * 32);
            bf16x8 a0 = *(const bf16x8*)&A[a0base + ((kk * 32 + klane) ^ asw)];
            bf16x8 a1 = *(const bf16x8*)&A[a1base + ((kk * 32 + klane) ^ asw)];
            MFMA(vU4[0], a0, vc); MFMA(vU4[1], a1, vc);
            if (kk < 6)       { vc = vd; vd = vn; }
            else if (kk == 6) { vc = vd; }
        }
        // r & q: W5/W6 frags shared over i AND both row-tiles (12 MFMA per frag)
        #pragma unroll
        for (int kk = 0; kk < 4; ++kk) {
            bf16x8 brr = *(const bf16x8*)(pV + 256 + kk * 32);
            bf16x8 bqq = *(const bf16x8*)(pV + 384 + kk * 32);
            #pragma unroll
            for (int i = 0; i < 3; ++i) {
                int kb = 384 + i * 128 + kk * 32;
                bf16x8 a0 = *(const bf16x8*)&A[a0base + ((kb + klane) ^ asw)];
                bf16x8 a1 = *(const bf16x8*)&A[a1base + ((kb + klane) ^ asw)];
                MFMA(vR[i][0], a0, brr); MFMA(vR[i][1], a1, brr);
                MFMA(vQ[i][0], a0, bqq); MFMA(vQ[i][1], a1, bqq);
            }
        }

        // ---- V epilogue: cross recombination + gate, guarded 12B stores ----
        int col = cw * 16 + l15;
        #pragma unroll
        for (int rt = 0; rt < 2; ++rt)
            #pragma unroll
            for (int rq = 0; rq < 4; ++rq) {
                int lr = rg * 32 + rt * 16 + lg * 4 + rq;
                int zr = z0 + lr;
                if (zr < n) {
                    f32x4 yv = *(const f32x4*)&Ylds[lr][0];
                    float g   = g2[rt][rq];
                    float u4v = vU4[rt][rq];
                    float v0 = yv[1]*u4v + yv[0]*vR[0][rt][rq] + yv[3]*vQ[1][rt][rq] - yv[2]*vQ[2][rt][rq];
                    float v1 = yv[2]*u4v + yv[0]*vR[1][rt][rq] + yv[1]*vQ[2][rt][rq] - yv[3]*vQ[0][rt][rq];
                    float v2 = yv[3]*u4v + yv[0]*vR[2][rt][rq] + yv[2]*vQ[0][rt][rq] - yv[1]*vQ[1][rt][rq];
                    size_t base = (size_t)zr * 640 + 256 + (size_t)col * 3;
                    out[base + 0] = v0 * g;
                    out[base + 1] = v1 * g;
                    out[base + 2] = v2 * g;
                }
            }
    }
}

extern "C" void kernel_launch(void* const* d_in, const int* in_sizes, int n_in,
                              void* d_out, int out_size, void* d_ws, size_t ws_size,
                              hipStream_t stream)
{
    (void)n_in; (void)out_size; (void)ws_size;
    const float* x  = (const float*)d_in[0];
    const float* y  = (const float*)d_in[1];
    const float* W0 = (const float*)d_in[2];
    const float* W1 = (const float*)d_in[3];
    const float* W2 = (const float*)d_in[4];
    const float* W3 = (const float*)d_in[5];
    const float* W4 = (const float*)d_in[6];
    const float* W5 = (const float*)d_in[7];
    const float* W6 = (const float*)d_in[8];
    const float* b  = (const float*)d_in[9];
    float* out = (float*)d_out;

    const int n = in_sizes[0] / 640;                // 100000

    bf16_t* WsT = (bf16_t*)d_ws;                    // 384*384 bf16
    bf16_t* WvT = WsT + 384 * 384;                  // 128*512 bf16 (total 425,984 B)

    const double c0 = std::sqrt(256.0 * 256.0 / 384.0);
    const double c1 = std::sqrt(256.0 * 128.0 / 384.0) / std::sqrt(3.0);
    const double c2 = std::sqrt(128.0 * 256.0 / 384.0);
    const double c3 = std::sqrt(128.0 * 128.0 / 384.0) / std::sqrt(3.0);
    const double c4 = std::sqrt(3.0 * 128.0 * 256.0 / 512.0) / std::sqrt(3.0);
    const double c5 = std::sqrt(3.0 * 128.0 * 128.0 / 512.0) / std::sqrt(3.0);
    const double c6 = std::sqrt(3.0 * 128.0 * 128.0 / 512.0) / std::sqrt(6.0);
    const double inv = 1.0 / std::sqrt(2560.0);

    // second moments of silu/sigmoid under N(0,1) via Simpson (matches hermgauss)
    double m_silu = 0.0, m_sig = 0.0;
    {
        const int M = 24000;
        const double a = -12.0, h = 24.0 / M;
        for (int k = 0; k <= M; ++k) {
            double t = a + h * k;
            double wgt = (k == 0 || k == M) ? 1.0 : ((k & 1) ? 4.0 : 2.0);
            double sg = 1.0 / (1.0 + std::exp(-t));
            double phi = std::exp(-0.5 * t * t) * 0.3989422804014327;
            m_silu += wgt * (t * sg) * (t * sg) * phi;
            m_sig  += wgt * sg * sg * phi;
        }
        m_silu *= h / 3.0; m_sig *= h / 3.0;
    }
    const float silu_c = (float)(1.0 / std::sqrt(m_silu));
    const float sig_c  = (float)(1.0 / std::sqrt(m_sig));

    prep_weights<<<(384 * 384 + 128 * 512 + 255) / 256, 256, 0, stream>>>(
        W0, W1, W2, W3, W4, W5, W6, WsT, WvT,
        (float)c0, (float)c1, (float)c2, (float)c3, (float)c4, (float)c5, (float)c6);

    const int grid = (n + BM - 1) / BM;             // 1563
    tp_fused<<<grid, 1024, 0, stream>>>(x, y, b, WsT, WvT, out, n,
                                        (float)inv, silu_c, sig_c);
}